// Round 1
// baseline (11087.208 us; speedup 1.0000x reference)
//
#include <hip/hip_runtime.h>
#include <hip/hip_bf16.h>

#define DHID 256
#define DPAD 257
#define MTOT (DPAD*DHID)   // 65792 columns (b,c) flattened
#define NROWS 2048         // N*L rows (n,i) flattened
#define JT 32              // j-tile in stage 2

// ---------------- Stage 1: T1/T2[r, b, c] = sum_a l1aug[r,a] * W[a,b,c] ----
// grid: (chunk/16, 257), block 256. Column m = b*256+c = blockIdx.y*256 + tid.
__global__ __launch_bounds__(256)
void stage1(const float* __restrict__ layer1,
            const float* __restrict__ W1,
            const float* __restrict__ W2,
            __hip_bfloat16* __restrict__ T1,
            __hip_bfloat16* __restrict__ T2,
            int row0)
{
    __shared__ float As[16*260];          // A tile, padded row stride (broadcast reads)
    const int t  = threadIdx.x;
    const int rb = blockIdx.x;
    const int m  = blockIdx.y * 256 + t;  // [0, 65792)
    const int r0 = row0 + rb*16;          // first global row of tile

    for (int k = t; k < 16*256; k += 256) {
        int rr = k >> 8, a = k & 255;
        As[rr*260 + a] = layer1[(size_t)(r0+rr)*DHID + a];
    }
    __syncthreads();

    float acc1[16], acc2[16];
    // a == 256 tail: l1aug = 1 -> just add W[256, m]
    const float w1t = W1[(size_t)256*MTOT + m];
    const float w2t = W2[(size_t)256*MTOT + m];
    #pragma unroll
    for (int rr = 0; rr < 16; ++rr) { acc1[rr] = w1t; acc2[rr] = w2t; }

    #pragma unroll 2
    for (int a = 0; a < 256; a += 4) {
        float w1[4], w2[4];
        #pragma unroll
        for (int q = 0; q < 4; ++q) {
            w1[q] = W1[(size_t)(a+q)*MTOT + m];
            w2[q] = W2[(size_t)(a+q)*MTOT + m];
        }
        #pragma unroll
        for (int rr = 0; rr < 16; ++rr) {
            float4 av = *(const float4*)&As[rr*260 + a];   // wave-uniform broadcast
            acc1[rr] += av.x*w1[0] + av.y*w1[1] + av.z*w1[2] + av.w*w1[3];
            acc2[rr] += av.x*w2[0] + av.y*w2[1] + av.z*w2[2] + av.w*w2[3];
        }
    }

    const int rloc0 = rb*16;   // chunk-local row
    #pragma unroll
    for (int rr = 0; rr < 16; ++rr) {
        T1[(size_t)(rloc0+rr)*MTOT + m] = __float2bfloat16(acc1[rr]);
        T2[(size_t)(rloc0+rr)*MTOT + m] = __float2bfloat16(acc2[rr]);
    }
}

// ---------------- Stage 2 (fused): per row r=(n,i) --------------------------
// U1[j,c] = sum_b l2aug[n,j,b] T1[r,b,c];  V = h * U
// P[j,d]  = sum_c V1[j,c] W3[c,d];  out[n,i,j] = sum_d P[j,d] V2[j,d]
// One block per row; thread t = c (phase A) = d (phase B). j-tiles of 32.
__global__ __launch_bounds__(256)
void stage2(const float* __restrict__ layer2,
            const float* __restrict__ h1g,
            const float* __restrict__ h2g,
            const float* __restrict__ W3,
            const __hip_bfloat16* __restrict__ T1c,
            const __hip_bfloat16* __restrict__ T2c,
            float* __restrict__ out,
            int row0)
{
    __shared__ float smA[JT*260];   // l2 tile -> V1 -> prods (time-multiplexed)
    __shared__ float smV2[JT*260];
    __shared__ float smP[JT*9];

    const int t    = threadIdx.x;
    const int rloc = blockIdx.x;
    const int r    = row0 + rloc;
    const int n    = r >> 8;

    const __hip_bfloat16* T1 = T1c + (size_t)rloc * MTOT;
    const __hip_bfloat16* T2 = T2c + (size_t)rloc * MTOT;
    const float* l2n = layer2 + (size_t)n * (256*256);
    const float hc1 = h1g[(size_t)r*DHID + t];
    const float hc2 = h2g[(size_t)r*DHID + t];

    // b == 256 tail: l2aug = 1
    const float t1tail = __bfloat162float(T1[(size_t)256*DHID + t]);
    const float t2tail = __bfloat162float(T2[(size_t)256*DHID + t]);

    for (int jt = 0; jt < 256/JT; ++jt) {
        const int j0 = jt * JT;

        for (int k = t; k < JT*256; k += 256) {
            int jj = k >> 8, bb = k & 255;
            smA[jj*260 + bb] = l2n[(size_t)(j0+jj)*DHID + bb];
        }
        __syncthreads();

        // ---- phase A ----
        float acc1[JT], acc2[JT];
        #pragma unroll
        for (int j = 0; j < JT; ++j) { acc1[j] = t1tail; acc2[j] = t2tail; }

        #pragma unroll 2
        for (int b = 0; b < 256; b += 4) {
            float a1[4], a2[4];
            #pragma unroll
            for (int q = 0; q < 4; ++q) {
                a1[q] = __bfloat162float(T1[(size_t)(b+q)*DHID + t]);
                a2[q] = __bfloat162float(T2[(size_t)(b+q)*DHID + t]);
            }
            #pragma unroll
            for (int j = 0; j < JT; ++j) {
                float4 lv = *(const float4*)&smA[j*260 + b];
                acc1[j] += lv.x*a1[0] + lv.y*a1[1] + lv.z*a1[2] + lv.w*a1[3];
                acc2[j] += lv.x*a2[0] + lv.y*a2[1] + lv.z*a2[2] + lv.w*a2[3];
            }
        }
        __syncthreads();   // all threads done reading smA (l2 tile)

        // ---- V = h * U into LDS ----
        #pragma unroll
        for (int j = 0; j < JT; ++j) {
            smA[j*260 + t]  = hc1 * acc1[j];
            smV2[j*260 + t] = hc2 * acc2[j];
        }
        __syncthreads();

        // ---- phase B: P[j, d=t] ----
        float P[JT];
        #pragma unroll
        for (int j = 0; j < JT; ++j) P[j] = 0.f;
        #pragma unroll 2
        for (int c = 0; c < 256; c += 4) {
            float w3[4];
            #pragma unroll
            for (int q = 0; q < 4; ++q) w3[q] = W3[(size_t)(c+q)*DHID + t];
            #pragma unroll
            for (int j = 0; j < JT; ++j) {
                float4 v1 = *(const float4*)&smA[j*260 + c];
                P[j] += v1.x*w3[0] + v1.y*w3[1] + v1.z*w3[2] + v1.w*w3[3];
            }
        }
        __syncthreads();   // done reading smA (V1)

        // ---- phase C: prods + reduce over d ----
        #pragma unroll
        for (int j = 0; j < JT; ++j)
            smA[j*260 + t] = P[j] * smV2[j*260 + t];
        __syncthreads();

        {
            int j = t >> 3, seg = t & 7;
            float s = 0.f;
            #pragma unroll
            for (int k = 0; k < 32; k += 4) {
                float4 v = *(const float4*)&smA[j*260 + seg*32 + k];
                s += v.x + v.y + v.z + v.w;
            }
            smP[j*9 + seg] = s;
        }
        __syncthreads();
        if (t < JT) {
            float s = 0.f;
            #pragma unroll
            for (int seg = 0; seg < 8; ++seg) s += smP[t*9 + seg];
            out[(size_t)r*DHID + j0 + t] = s;
        }
        __syncthreads();
    }
}

extern "C" void kernel_launch(void* const* d_in, const int* in_sizes, int n_in,
                              void* d_out, int out_size, void* d_ws, size_t ws_size,
                              hipStream_t stream) {
    const float* layer1 = (const float*)d_in[0];
    const float* layer2 = (const float*)d_in[1];
    const float* h1     = (const float*)d_in[2];
    const float* h2     = (const float*)d_in[3];
    const float* W1     = (const float*)d_in[4];
    const float* W2     = (const float*)d_in[5];
    const float* W3     = (const float*)d_in[6];
    float* out = (float*)d_out;

    // T1+T2 scratch in bf16; chunk rows if ws is small (ws_size constant -> same work every call)
    const size_t per_row = (size_t)2 * MTOT * sizeof(__hip_bfloat16);
    int chunk = 2048;
    while ((size_t)chunk * per_row > ws_size && chunk > 64) chunk >>= 1;

    __hip_bfloat16* T1 = (__hip_bfloat16*)d_ws;
    __hip_bfloat16* T2 = T1 + (size_t)chunk * MTOT;

    for (int row0 = 0; row0 < NROWS; row0 += chunk) {
        dim3 g1(chunk/16, DPAD);
        stage1<<<g1, 256, 0, stream>>>(layer1, W1, W2, T1, T2, row0);
        stage2<<<dim3(chunk), 256, 0, stream>>>(layer2, h1, h2, W3, T1, T2, out, row0);
    }
}

// Round 3
// 1106.972 us; speedup vs baseline: 10.0158x; 10.0158x over previous
//
#include <hip/hip_runtime.h>

typedef __attribute__((ext_vector_type(4))) float f32x4;
typedef __attribute__((ext_vector_type(8))) short s16x8;

#define MTOTW 65792   // 257*256: fp32 W stride per a-index

__device__ __forceinline__ short f2bf(float f) {
    unsigned u = __builtin_bit_cast(unsigned, f);
    u = (u + 0x7fffu + ((u >> 16) & 1u)) >> 16;   // RNE
    return (short)u;
}

// ---------- prep: l1,l2 -> bf16 (flat) ----------
__global__ __launch_bounds__(256) void conv_bf16(
    const float* __restrict__ a, const float* __restrict__ b,
    short* __restrict__ ao, short* __restrict__ bo)
{
    int i = blockIdx.x * 256 + threadIdx.x;       // 262144 threads, float4 each
    const int HALF = 131072;
    float4 v; short* dst;
    if (i < HALF) { v = ((const float4*)a)[i]; dst = ao + (size_t)i * 4; }
    else          { v = ((const float4*)b)[i - HALF]; dst = bo + (size_t)(i - HALF) * 4; }
    short4 o; o.x = f2bf(v.x); o.y = f2bf(v.y); o.z = f2bf(v.z); o.w = f2bf(v.w);
    *(short4*)dst = o;
}

// ---------- prep: W3t[d][c] = bf16(W3[c][d]) ----------
__global__ __launch_bounds__(256) void prep_w3t(
    const float* __restrict__ W3, short* __restrict__ W3t)
{
    __shared__ float ld[32][33];
    int t = threadIdx.x, bx = blockIdx.x;
    int c0 = (bx >> 3) * 32, d0 = (bx & 7) * 32;
    int cr = t >> 3, dq = t & 7;
    float4 v = *(const float4*)&W3[(size_t)(c0 + cr) * 256 + d0 + dq * 4];
    ld[cr][dq*4+0] = v.x; ld[cr][dq*4+1] = v.y; ld[cr][dq*4+2] = v.z; ld[cr][dq*4+3] = v.w;
    __syncthreads();
    int dr = t >> 3, cq = t & 7;
    short4 o;
    o.x = f2bf(ld[cq*4+0][dr]); o.y = f2bf(ld[cq*4+1][dr]);
    o.z = f2bf(ld[cq*4+2][dr]); o.w = f2bf(ld[cq*4+3][dr]);
    *(short4*)&W3t[(size_t)(d0 + dr) * 256 + c0 + cq * 4] = o;
}

// ---------- prep: Wp[c][b][a] = bf16(W[a][b][c]), a,b,c in [0,256) ----------
__global__ __launch_bounds__(256) void prep_wp(
    const float* __restrict__ W1, const float* __restrict__ W2,
    short* __restrict__ Wp1, short* __restrict__ Wp2)
{
    __shared__ float ld[32][33];
    int t = threadIdx.x, bx = blockIdx.x;
    int b = blockIdx.y;
    const float* W = blockIdx.z ? W2 : W1;
    short* Wp = blockIdx.z ? Wp2 : Wp1;
    int a0 = (bx >> 3) * 32, c0 = (bx & 7) * 32;
    int ar = t >> 3, cq = t & 7;
    float4 v = *(const float4*)&W[(size_t)(a0 + ar) * MTOTW + (size_t)b * 256 + c0 + cq * 4];
    ld[ar][cq*4+0] = v.x; ld[ar][cq*4+1] = v.y; ld[ar][cq*4+2] = v.z; ld[ar][cq*4+3] = v.w;
    __syncthreads();
    int cr = t >> 3, aq = t & 7;
    short4 o;
    o.x = f2bf(ld[aq*4+0][cr]); o.y = f2bf(ld[aq*4+1][cr]);
    o.z = f2bf(ld[aq*4+2][cr]); o.w = f2bf(ld[aq*4+3][cr]);
    *(short4*)&Wp[((size_t)(c0 + cr) * 256 + b) * 256 + a0 + aq * 4] = o;
}

// ---------- tails: T?tail[r][c] = sum_a l1aug[r,a] * W[a][256][c]  (fp32) ----------
__global__ __launch_bounds__(256) void t_tail(
    const float* __restrict__ layer1, const float* __restrict__ W1,
    const float* __restrict__ W2, float* __restrict__ tail1, float* __restrict__ tail2)
{
    __shared__ float As[16][257];
    int t = threadIdx.x; int r0 = blockIdx.x * 16;
    for (int k = t; k < 16 * 256; k += 256)
        As[k >> 8][k & 255] = layer1[(size_t)(r0 + (k >> 8)) * 256 + (k & 255)];
    __syncthreads();
    float a1[16], a2[16];
    float w1 = W1[(size_t)256 * MTOTW + 65536 + t];   // a=256 (coeff 1)
    float w2 = W2[(size_t)256 * MTOTW + 65536 + t];
    #pragma unroll
    for (int rr = 0; rr < 16; ++rr) { a1[rr] = w1; a2[rr] = w2; }
    for (int a = 0; a < 256; ++a) {
        float x1 = W1[(size_t)a * MTOTW + 65536 + t];
        float x2 = W2[(size_t)a * MTOTW + 65536 + t];
        #pragma unroll
        for (int rr = 0; rr < 16; ++rr) { a1[rr] += As[rr][a] * x1; a2[rr] += As[rr][a] * x2; }
    }
    for (int rr = 0; rr < 16; ++rr) {
        tail1[(size_t)(r0 + rr) * 256 + t] = a1[rr];
        tail2[(size_t)(r0 + rr) * 256 + t] = a2[rr];
    }
}

// ---------- stage1: T[rl][c][b] = bf16( sum_a l1b[r][a]*Wp[c][b][a] + W[256][b][c] ) ----------
__global__ __launch_bounds__(256, 2) void stage1(
    const short* __restrict__ l1b,
    const short* __restrict__ Wp1, const short* __restrict__ Wp2,
    const float* __restrict__ W1, const float* __restrict__ W2,
    short* __restrict__ T1, short* __restrict__ T2, int row0)
{
    __shared__ __align__(16) short Al[128 * 32];   // [m][k], 64B rows
    __shared__ __align__(16) short Bl[128 * 32];   // [n(b)][k]
    int t = threadIdx.x, w = t >> 6, lane = t & 63;
    int rt = blockIdx.x, bt = blockIdx.y, zc = blockIdx.z;
    int c = zc >> 1, ten = zc & 1;
    const short* Wp = ten ? Wp2 : Wp1;
    const float* Wf = ten ? W2 : W1;
    short* T = ten ? T2 : T1;
    int r0g = row0 + rt * 128;
    int b0 = bt * 128;
    const short* Ab = l1b + (size_t)r0g * 256;
    const short* Bb = Wp + ((size_t)c * 256 + b0) * 256;

    f32x4 acc[4][4] = {};
    int m0w = (w >> 1) * 64, n0w = (w & 1) * 64;

    for (int k0 = 0; k0 < 256; k0 += 32) {
        __syncthreads();
        #pragma unroll
        for (int q = 0; q < 4; ++q) {           // 512 A + 512 B stores
            int id = t + q * 256;
            if (id < 512) {
                int m = id >> 2, kq = id & 3;
                *(int4*)&Al[m * 32 + kq * 8] = *(const int4*)&Ab[(size_t)m * 256 + k0 + kq * 8];
            } else {
                int bid = id - 512; int m = bid >> 2, kq = bid & 3;
                *(int4*)&Bl[m * 32 + kq * 8] = *(const int4*)&Bb[(size_t)m * 256 + k0 + kq * 8];
            }
        }
        __syncthreads();
        s16x8 af[4], bf[4];
        #pragma unroll
        for (int i = 0; i < 4; ++i) {
            af[i] = *(const s16x8*)&Al[(m0w + i * 16 + (lane & 15)) * 32 + (lane >> 4) * 8];
            bf[i] = *(const s16x8*)&Bl[(n0w + i * 16 + (lane & 15)) * 32 + (lane >> 4) * 8];
        }
        #pragma unroll
        for (int mi = 0; mi < 4; ++mi)
            #pragma unroll
            for (int ni = 0; ni < 4; ++ni)
                acc[mi][ni] = __builtin_amdgcn_mfma_f32_16x16x32_bf16(af[mi], bf[ni], acc[mi][ni], 0, 0, 0);
    }

    #pragma unroll
    for (int ni = 0; ni < 4; ++ni) {
        int b = b0 + n0w + ni * 16 + (lane & 15);
        float tl = Wf[(size_t)256 * MTOTW + (size_t)b * 256 + c];   // a=256 tail, fp32
        #pragma unroll
        for (int mi = 0; mi < 4; ++mi) {
            int rl = rt * 128 + m0w + mi * 16 + (lane >> 4) * 4;    // chunk-local row
            #pragma unroll
            for (int reg = 0; reg < 4; ++reg)
                T[((size_t)(rl + reg) * 256 + c) * 256 + b] = f2bf(acc[mi][ni][reg] + tl);
        }
    }
}

// ---------- stage2: fused U1 -> V1(LDS) -> U2(regs) -> P -> dot ----------
__global__ __launch_bounds__(256, 2) void stage2(
    const short* __restrict__ l2b,
    const short* __restrict__ T1, const short* __restrict__ T2,
    const float* __restrict__ tail1, const float* __restrict__ tail2,
    const float* __restrict__ h1, const float* __restrict__ h2,
    const short* __restrict__ W3t, float* __restrict__ out, int row0)
{
    __shared__ __align__(16) short Al[64 * 32];    // l2 j-tile [j][k]
    __shared__ __align__(16) short Bl[256 * 32];   // [n][k], n = c or d
    __shared__ __align__(16) short V1[64 * 264];   // [j][c]
    __shared__ float part[64 * 4];
    int t = threadIdx.x, w = t >> 6, lane = t & 63;
    int jt = blockIdx.x, rl = blockIdx.y;
    int rg = row0 + rl, n = rg >> 8, j0 = jt * 64;
    const short* Arow = l2b + ((size_t)n * 256 + j0) * 256;
    const short* Tt1 = T1 + (size_t)rl * 65536;
    const short* Tt2 = T2 + (size_t)rl * 65536;
    int n0w = w * 64;

    f32x4 v2[4][4];
    for (int ph = 0; ph < 3; ++ph) {
        const short* Bsrc = (ph == 0) ? Tt1 : (ph == 1) ? Tt2 : W3t;
        f32x4 acc[4][4] = {};
        for (int k0 = 0; k0 < 256; k0 += 32) {
            __syncthreads();
            if (ph < 2) {
                // Al: 64 rows x 4 chunks = 256 stores; Bl: 256 rows x 4 = 1024 -> 5 rounds
                #pragma unroll
                for (int q = 0; q < 5; ++q) {
                    int id = t + q * 256;
                    if (id < 256) {
                        int m = id >> 2, kq = id & 3;
                        *(int4*)&Al[m * 32 + kq * 8] = *(const int4*)&Arow[(size_t)m * 256 + k0 + kq * 8];
                    } else {
                        int bid = id - 256; int m = bid >> 2, kq = bid & 3;
                        *(int4*)&Bl[m * 32 + kq * 8] = *(const int4*)&Bsrc[(size_t)m * 256 + k0 + kq * 8];
                    }
                }
            } else {
                // Bl only: 1024 stores -> 4 rounds
                #pragma unroll
                for (int q = 0; q < 4; ++q) {
                    int id = t + q * 256; int m = id >> 2, kq = id & 3;
                    *(int4*)&Bl[m * 32 + kq * 8] = *(const int4*)&Bsrc[(size_t)m * 256 + k0 + kq * 8];
                }
            }
            __syncthreads();
            s16x8 af[4], bf[4];
            #pragma unroll
            for (int i = 0; i < 4; ++i) {
                if (ph < 2)
                    af[i] = *(const s16x8*)&Al[(i * 16 + (lane & 15)) * 32 + (lane >> 4) * 8];
                else
                    af[i] = *(const s16x8*)&V1[(i * 16 + (lane & 15)) * 264 + k0 + (lane >> 4) * 8];
                bf[i] = *(const s16x8*)&Bl[(n0w + i * 16 + (lane & 15)) * 32 + (lane >> 4) * 8];
            }
            #pragma unroll
            for (int mi = 0; mi < 4; ++mi)
                #pragma unroll
                for (int ni = 0; ni < 4; ++ni)
                    acc[mi][ni] = __builtin_amdgcn_mfma_f32_16x16x32_bf16(af[mi], bf[ni], acc[mi][ni], 0, 0, 0);
        }

        if (ph == 0) {          // V1 = h1 * (U1 + tail1) -> LDS bf16
            #pragma unroll
            for (int ni = 0; ni < 4; ++ni) {
                int c = n0w + ni * 16 + (lane & 15);
                float hh = h1[(size_t)rg * 256 + c];
                float tl = tail1[(size_t)rg * 256 + c];
                #pragma unroll
                for (int mi = 0; mi < 4; ++mi)
                    #pragma unroll
                    for (int reg = 0; reg < 4; ++reg) {
                        int j = mi * 16 + (lane >> 4) * 4 + reg;
                        V1[j * 264 + c] = f2bf(hh * (acc[mi][ni][reg] + tl));
                    }
            }
        } else if (ph == 1) {   // V2 = h2 * (U2 + tail2) -> regs
            #pragma unroll
            for (int ni = 0; ni < 4; ++ni) {
                int c = n0w + ni * 16 + (lane & 15);
                float hh = h2[(size_t)rg * 256 + c];
                float tl = tail2[(size_t)rg * 256 + c];
                #pragma unroll
                for (int mi = 0; mi < 4; ++mi)
                    #pragma unroll
                    for (int reg = 0; reg < 4; ++reg)
                        v2[mi][ni][reg] = hh * (acc[mi][ni][reg] + tl);
            }
        } else {                // out[j] = sum_d P[j][d] * V2[j][d]
            #pragma unroll
            for (int mi = 0; mi < 4; ++mi)
                #pragma unroll
                for (int reg = 0; reg < 4; ++reg) {
                    float s = 0.f;
                    #pragma unroll
                    for (int ni = 0; ni < 4; ++ni) s += acc[mi][ni][reg] * v2[mi][ni][reg];
                    s += __shfl_xor(s, 1); s += __shfl_xor(s, 2);
                    s += __shfl_xor(s, 4); s += __shfl_xor(s, 8);
                    if ((lane & 15) == 0)
                        part[(mi * 16 + (lane >> 4) * 4 + reg) * 4 + w] = s;
                }
            __syncthreads();
            if (t < 64)
                out[(size_t)rg * 256 + j0 + t] = part[t*4] + part[t*4+1] + part[t*4+2] + part[t*4+3];
        }
    }
}

extern "C" void kernel_launch(void* const* d_in, const int* in_sizes, int n_in,
                              void* d_out, int out_size, void* d_ws, size_t ws_size,
                              hipStream_t stream) {
    const float* layer1 = (const float*)d_in[0];
    const float* layer2 = (const float*)d_in[1];
    const float* h1     = (const float*)d_in[2];
    const float* h2     = (const float*)d_in[3];
    const float* W1     = (const float*)d_in[4];
    const float* W2     = (const float*)d_in[5];
    const float* W3     = (const float*)d_in[6];
    float* out = (float*)d_out;

    short* Wp1  = (short*)d_ws;                  // 256^3 bf16 = 33.55 MB
    short* Wp2  = Wp1 + 16777216;
    short* l1b  = Wp2 + 16777216;                // 2048x256
    short* l2b  = l1b + 524288;
    short* W3t  = l2b + 524288;                  // 256x256
    float* tail1 = (float*)(W3t + 65536);        // 2048x256 fp32
    float* tail2 = tail1 + 524288;
    short* T1   = (short*)(tail2 + 524288);
    const size_t head = 73531392;                // bytes up to T1
    int chunk = 2048;
    while (head + (size_t)chunk * 262144 > ws_size && chunk > 128) chunk >>= 1;
    short* T2 = T1 + (size_t)chunk * 65536;

    conv_bf16<<<1024, 256, 0, stream>>>(layer1, layer2, l1b, l2b);
    prep_w3t<<<64, 256, 0, stream>>>(W3, W3t);
    prep_wp<<<dim3(64, 256, 2), 256, 0, stream>>>(W1, W2, Wp1, Wp2);
    t_tail<<<128, 256, 0, stream>>>(layer1, W1, W2, tail1, tail2);

    for (int row0 = 0; row0 < 2048; row0 += chunk) {
        stage1<<<dim3(chunk / 128, 2, 512), 256, 0, stream>>>(
            l1b, Wp1, Wp2, W1, W2, T1, T2, row0);
        stage2<<<dim3(4, chunk), 256, 0, stream>>>(
            l2b, T1, T2, tail1, tail2, h1, h2, W3t, out, row0);
    }
}

// Round 4
// 1076.679 us; speedup vs baseline: 10.2976x; 1.0281x over previous
//
#include <hip/hip_runtime.h>

typedef __attribute__((ext_vector_type(4))) float f32x4;
typedef __attribute__((ext_vector_type(8))) short s16x8;

#define MTOTW 65792   // 257*256: fp32 W stride per a-index

__device__ __forceinline__ short f2bf(float f) {
    unsigned u = __builtin_bit_cast(unsigned, f);
    u = (u + 0x7fffu + ((u >> 16) & 1u)) >> 16;   // RNE
    return (short)u;
}

// async global->LDS, 16B per lane: LDS dest = uniform base + lane*16 (m97/m104)
__device__ __forceinline__ void gl16(const void* g, void* l) {
    __builtin_amdgcn_global_load_lds(
        (const __attribute__((address_space(1))) unsigned int*)g,
        (__attribute__((address_space(3))) unsigned int*)l, 16, 0, 0);
}

// ---------- prep: l1,l2 -> bf16 (flat) ----------
__global__ __launch_bounds__(256) void conv_bf16(
    const float* __restrict__ a, const float* __restrict__ b,
    short* __restrict__ ao, short* __restrict__ bo)
{
    int i = blockIdx.x * 256 + threadIdx.x;
    const int HALF = 131072;
    float4 v; short* dst;
    if (i < HALF) { v = ((const float4*)a)[i]; dst = ao + (size_t)i * 4; }
    else          { v = ((const float4*)b)[i - HALF]; dst = bo + (size_t)(i - HALF) * 4; }
    short4 o; o.x = f2bf(v.x); o.y = f2bf(v.y); o.z = f2bf(v.z); o.w = f2bf(v.w);
    *(short4*)dst = o;
}

// ---------- prep: W3t[d][c] = bf16(W3[c][d]) ----------
__global__ __launch_bounds__(256) void prep_w3t(
    const float* __restrict__ W3, short* __restrict__ W3t)
{
    __shared__ float ld[32][33];
    int t = threadIdx.x, bx = blockIdx.x;
    int c0 = (bx >> 3) * 32, d0 = (bx & 7) * 32;
    int cr = t >> 3, dq = t & 7;
    float4 v = *(const float4*)&W3[(size_t)(c0 + cr) * 256 + d0 + dq * 4];
    ld[cr][dq*4+0] = v.x; ld[cr][dq*4+1] = v.y; ld[cr][dq*4+2] = v.z; ld[cr][dq*4+3] = v.w;
    __syncthreads();
    int dr = t >> 3, cq = t & 7;
    short4 o;
    o.x = f2bf(ld[cq*4+0][dr]); o.y = f2bf(ld[cq*4+1][dr]);
    o.z = f2bf(ld[cq*4+2][dr]); o.w = f2bf(ld[cq*4+3][dr]);
    *(short4*)&W3t[(size_t)(d0 + dr) * 256 + c0 + cq * 4] = o;
}

// ---------- prep: Wtp[c][a] = bf16(W[a][256][c]) (the b=256 plane, transposed) ----------
__global__ __launch_bounds__(256) void prep_wtail(
    const float* __restrict__ W1, const float* __restrict__ W2,
    short* __restrict__ Wtp1, short* __restrict__ Wtp2)
{
    __shared__ float ld[32][33];
    int t = threadIdx.x, bx = blockIdx.x;
    const float* W = blockIdx.y ? W2 : W1;
    short* Wtp = blockIdx.y ? Wtp2 : Wtp1;
    int a0 = (bx >> 3) * 32, c0 = (bx & 7) * 32;
    int ar = t >> 3, cq = t & 7;
    float4 v = *(const float4*)&W[(size_t)(a0 + ar) * MTOTW + 65536 + c0 + cq * 4];
    ld[ar][cq*4+0] = v.x; ld[ar][cq*4+1] = v.y; ld[ar][cq*4+2] = v.z; ld[ar][cq*4+3] = v.w;
    __syncthreads();
    int cr = t >> 3, aq = t & 7;
    short4 o;
    o.x = f2bf(ld[aq*4+0][cr]); o.y = f2bf(ld[aq*4+1][cr]);
    o.z = f2bf(ld[aq*4+2][cr]); o.w = f2bf(ld[aq*4+3][cr]);
    *(short4*)&Wtp[(size_t)(c0 + cr) * 256 + a0 + aq * 4] = o;
}

// ---------- prep: Wp[c][b][a] = bf16(W[a][b][c]) ----------
__global__ __launch_bounds__(256) void prep_wp(
    const float* __restrict__ W1, const float* __restrict__ W2,
    short* __restrict__ Wp1, short* __restrict__ Wp2)
{
    __shared__ float ld[32][33];
    int t = threadIdx.x, bx = blockIdx.x;
    int b = blockIdx.y;
    const float* W = blockIdx.z ? W2 : W1;
    short* Wp = blockIdx.z ? Wp2 : Wp1;
    int a0 = (bx >> 3) * 32, c0 = (bx & 7) * 32;
    int ar = t >> 3, cq = t & 7;
    float4 v = *(const float4*)&W[(size_t)(a0 + ar) * MTOTW + (size_t)b * 256 + c0 + cq * 4];
    ld[ar][cq*4+0] = v.x; ld[ar][cq*4+1] = v.y; ld[ar][cq*4+2] = v.z; ld[ar][cq*4+3] = v.w;
    __syncthreads();
    int cr = t >> 3, aq = t & 7;
    short4 o;
    o.x = f2bf(ld[aq*4+0][cr]); o.y = f2bf(ld[aq*4+1][cr]);
    o.z = f2bf(ld[aq*4+2][cr]); o.w = f2bf(ld[aq*4+3][cr]);
    *(short4*)&Wp[((size_t)(c0 + cr) * 256 + b) * 256 + a0 + aq * 4] = o;
}

// ---------- tail_mfma: tail[r][c] = sum_{a<256} l1b[r][a]*Wtp[c][a] + W[256][256][c] ----------
// grid (16 rt, 2 nt, 2 ten), block 256; M=128 N=128 K=256
__global__ __launch_bounds__(256, 2) void tail_mfma(
    const short* __restrict__ l1b,
    const short* __restrict__ Wtp1, const short* __restrict__ Wtp2,
    const float* __restrict__ W1, const float* __restrict__ W2,
    float* __restrict__ tail1, float* __restrict__ tail2)
{
    __shared__ __align__(16) short Al[128 * 32];
    __shared__ __align__(16) short Bl[128 * 32];
    int t = threadIdx.x, w = t >> 6, lane = t & 63;
    int l4 = lane >> 2, kq = lane & 3;
    int rt = blockIdx.x, nt = blockIdx.y, ten = blockIdx.z;
    const short* Wtp = ten ? Wtp2 : Wtp1;
    const float* Wf = ten ? W2 : W1;
    float* tail = ten ? tail2 : tail1;
    const short* Ab = l1b + (size_t)(rt * 128) * 256;
    const short* Bb = Wtp + (size_t)(nt * 128) * 256;

    f32x4 acc[4][4] = {};
    int m0w = (w >> 1) * 64, n0w = (w & 1) * 64;

    for (int k0 = 0; k0 < 256; k0 += 32) {
        __syncthreads();
        #pragma unroll
        for (int q = 0; q < 4; ++q) {
            int seg = w * 4 + q;
            if (seg < 8)
                gl16(Ab + (size_t)(seg * 16 + l4) * 256 + k0 + kq * 8, &Al[seg * 512]);
            else
                gl16(Bb + (size_t)((seg - 8) * 16 + l4) * 256 + k0 + kq * 8, &Bl[(seg - 8) * 512]);
        }
        __syncthreads();
        s16x8 af[4], bf[4];
        #pragma unroll
        for (int i = 0; i < 4; ++i) {
            af[i] = *(const s16x8*)&Al[(m0w + i * 16 + (lane & 15)) * 32 + (lane >> 4) * 8];
            bf[i] = *(const s16x8*)&Bl[(n0w + i * 16 + (lane & 15)) * 32 + (lane >> 4) * 8];
        }
        #pragma unroll
        for (int mi = 0; mi < 4; ++mi)
            #pragma unroll
            for (int ni = 0; ni < 4; ++ni)
                acc[mi][ni] = __builtin_amdgcn_mfma_f32_16x16x32_bf16(af[mi], bf[ni], acc[mi][ni], 0, 0, 0);
    }
    #pragma unroll
    for (int ni = 0; ni < 4; ++ni) {
        int c = nt * 128 + n0w + ni * 16 + (lane & 15);
        float tl = Wf[(size_t)256 * MTOTW + 65536 + c];   // a=256,b=256 term (coeff 1)
        #pragma unroll
        for (int mi = 0; mi < 4; ++mi) {
            int r = rt * 128 + m0w + mi * 16 + (lane >> 4) * 4;
            #pragma unroll
            for (int reg = 0; reg < 4; ++reg)
                tail[(size_t)(r + reg) * 256 + c] = acc[mi][ni][reg] + tl;
        }
    }
}

// ---------- stage1: T[rl][c][b] = bf16( sum_a l1b[r][a]*Wp[c][b][a] + W[256][b][c] ) ----------
__global__ __launch_bounds__(256, 2) void stage1(
    const short* __restrict__ l1b,
    const short* __restrict__ Wp1, const short* __restrict__ Wp2,
    const float* __restrict__ W1, const float* __restrict__ W2,
    short* __restrict__ T1, short* __restrict__ T2, int row0)
{
    __shared__ __align__(16) short Al[128 * 32];
    __shared__ __align__(16) short Bl[128 * 32];
    __shared__ __align__(16) short Cep[4 * 4096];   // per-wave 64x64 bf16 repack
    int t = threadIdx.x, w = t >> 6, lane = t & 63;
    int l4 = lane >> 2, kq = lane & 3;
    int rt = blockIdx.x, bt = blockIdx.y, zc = blockIdx.z;
    int c = zc >> 1, ten = zc & 1;
    const short* Wp = ten ? Wp2 : Wp1;
    const float* Wf = ten ? W2 : W1;
    short* T = ten ? T2 : T1;
    int r0g = row0 + rt * 128;
    int b0 = bt * 128;
    const short* Ab = l1b + (size_t)r0g * 256;
    const short* Bb = Wp + ((size_t)c * 256 + b0) * 256;

    f32x4 acc[4][4] = {};
    int m0w = (w >> 1) * 64, n0w = (w & 1) * 64;

    for (int k0 = 0; k0 < 256; k0 += 32) {
        __syncthreads();
        #pragma unroll
        for (int q = 0; q < 4; ++q) {
            int seg = w * 4 + q;
            if (seg < 8)
                gl16(Ab + (size_t)(seg * 16 + l4) * 256 + k0 + kq * 8, &Al[seg * 512]);
            else
                gl16(Bb + (size_t)((seg - 8) * 16 + l4) * 256 + k0 + kq * 8, &Bl[(seg - 8) * 512]);
        }
        __syncthreads();
        s16x8 af[4], bf[4];
        #pragma unroll
        for (int i = 0; i < 4; ++i) {
            af[i] = *(const s16x8*)&Al[(m0w + i * 16 + (lane & 15)) * 32 + (lane >> 4) * 8];
            bf[i] = *(const s16x8*)&Bl[(n0w + i * 16 + (lane & 15)) * 32 + (lane >> 4) * 8];
        }
        #pragma unroll
        for (int mi = 0; mi < 4; ++mi)
            #pragma unroll
            for (int ni = 0; ni < 4; ++ni)
                acc[mi][ni] = __builtin_amdgcn_mfma_f32_16x16x32_bf16(af[mi], bf[ni], acc[mi][ni], 0, 0, 0);
    }

    // epilogue: repack wave's 64x64 through LDS, store dwordx4 (128B runs)
    short* Cw = &Cep[w * 4096];
    #pragma unroll
    for (int ni = 0; ni < 4; ++ni) {
        int b = b0 + n0w + ni * 16 + (lane & 15);
        float tl = Wf[(size_t)256 * MTOTW + (size_t)b * 256 + c];   // a=256 tail, fp32
        #pragma unroll
        for (int mi = 0; mi < 4; ++mi)
            #pragma unroll
            for (int reg = 0; reg < 4; ++reg) {
                int lr = mi * 16 + (lane >> 4) * 4 + reg;           // wave-local row
                int lc = ni * 16 + (lane & 15);                     // wave-local col
                Cw[lr * 64 + lc] = f2bf(acc[mi][ni][reg] + tl);
            }
    }
    #pragma unroll
    for (int s = 0; s < 8; ++s) {
        int row = s * 8 + (lane >> 3);
        int co = (lane & 7) * 8;
        int rl = rt * 128 + m0w + row;                              // chunk-local row
        int gb = b0 + n0w + co;
        *(int4*)&T[((size_t)rl * 256 + c) * 256 + gb] = *(int4*)&Cw[row * 64 + co];
    }
}

// ---------- stage2: merged U1/U2 (shared A), then V1(LDS)->P->dot ----------
// grid (4 j-tiles, chunk rows), block 256; per phase-A kstep: dual-B MFMA
__global__ __launch_bounds__(256, 2) void stage2(
    const short* __restrict__ l2b,
    const short* __restrict__ T1, const short* __restrict__ T2,
    const float* __restrict__ tail1, const float* __restrict__ tail2,
    const float* __restrict__ h1, const float* __restrict__ h2,
    const short* __restrict__ W3t, float* __restrict__ out, int row0)
{
    __shared__ __align__(16) short Al[64 * 32];
    __shared__ __align__(16) short B1l[256 * 32];
    __shared__ __align__(16) short B2l[256 * 32];
    __shared__ __align__(16) short V1[64 * 264];
    __shared__ float part[64 * 4];
    int t = threadIdx.x, w = t >> 6, lane = t & 63;
    int l4 = lane >> 2, kq = lane & 3;
    int jt = blockIdx.x, rl = blockIdx.y;
    int rg = row0 + rl, n = rg >> 8, j0 = jt * 64;
    const short* Arow = l2b + ((size_t)n * 256 + j0) * 256;
    const short* Tt1 = T1 + (size_t)rl * 65536;
    const short* Tt2 = T2 + (size_t)rl * 65536;
    int n0w = w * 64;

    // ---- phase A: U1 and U2 together (A shared) ----
    f32x4 acc1[4][4] = {}, acc2[4][4] = {};
    for (int k0 = 0; k0 < 256; k0 += 32) {
        __syncthreads();
        #pragma unroll
        for (int q = 0; q < 9; ++q) {              // 4 Al + 16 B1 + 16 B2 = 36 segs
            int seg = w * 9 + q;
            const short* gb; short* lb;
            if (seg < 4)       { gb = Arow + (size_t)(seg * 16 + l4) * 256;        lb = &Al[seg * 512]; }
            else if (seg < 20) { int s = seg - 4;  gb = Tt1 + (size_t)(s * 16 + l4) * 256; lb = &B1l[s * 512]; }
            else               { int s = seg - 20; gb = Tt2 + (size_t)(s * 16 + l4) * 256; lb = &B2l[s * 512]; }
            gl16(gb + k0 + kq * 8, lb);
        }
        __syncthreads();
        s16x8 af[4], b1[4], b2[4];
        #pragma unroll
        for (int i = 0; i < 4; ++i) {
            af[i] = *(const s16x8*)&Al[(i * 16 + (lane & 15)) * 32 + (lane >> 4) * 8];
            b1[i] = *(const s16x8*)&B1l[(n0w + i * 16 + (lane & 15)) * 32 + (lane >> 4) * 8];
            b2[i] = *(const s16x8*)&B2l[(n0w + i * 16 + (lane & 15)) * 32 + (lane >> 4) * 8];
        }
        #pragma unroll
        for (int mi = 0; mi < 4; ++mi)
            #pragma unroll
            for (int ni = 0; ni < 4; ++ni) {
                acc1[mi][ni] = __builtin_amdgcn_mfma_f32_16x16x32_bf16(af[mi], b1[ni], acc1[mi][ni], 0, 0, 0);
                acc2[mi][ni] = __builtin_amdgcn_mfma_f32_16x16x32_bf16(af[mi], b2[ni], acc2[mi][ni], 0, 0, 0);
            }
    }

    // V1 = h1*(U1+tail1) -> LDS bf16 ; v2 = h2*(U2+tail2) -> regs
    f32x4 v2[4][4];
    #pragma unroll
    for (int ni = 0; ni < 4; ++ni) {
        int c = n0w + ni * 16 + (lane & 15);
        float hh1 = h1[(size_t)rg * 256 + c], tl1 = tail1[(size_t)rg * 256 + c];
        float hh2 = h2[(size_t)rg * 256 + c], tl2 = tail2[(size_t)rg * 256 + c];
        #pragma unroll
        for (int mi = 0; mi < 4; ++mi)
            #pragma unroll
            for (int reg = 0; reg < 4; ++reg) {
                int j = mi * 16 + (lane >> 4) * 4 + reg;
                V1[j * 264 + c] = f2bf(hh1 * (acc1[mi][ni][reg] + tl1));
                v2[mi][ni][reg] = hh2 * (acc2[mi][ni][reg] + tl2);
            }
    }

    // ---- phase B: P = V1 @ W3t^T (A from V1-LDS, B=W3t into B1l) ----
    f32x4 accP[4][4] = {};
    for (int k0 = 0; k0 < 256; k0 += 32) {
        __syncthreads();
        #pragma unroll
        for (int q = 0; q < 4; ++q) {
            int s = w * 4 + q;
            gl16(W3t + (size_t)(s * 16 + l4) * 256 + k0 + kq * 8, &B1l[s * 512]);
        }
        __syncthreads();
        s16x8 af[4], bf[4];
        #pragma unroll
        for (int i = 0; i < 4; ++i) {
            af[i] = *(const s16x8*)&V1[(i * 16 + (lane & 15)) * 264 + k0 + (lane >> 4) * 8];
            bf[i] = *(const s16x8*)&B1l[(n0w + i * 16 + (lane & 15)) * 32 + (lane >> 4) * 8];
        }
        #pragma unroll
        for (int mi = 0; mi < 4; ++mi)
            #pragma unroll
            for (int ni = 0; ni < 4; ++ni)
                accP[mi][ni] = __builtin_amdgcn_mfma_f32_16x16x32_bf16(af[mi], bf[ni], accP[mi][ni], 0, 0, 0);
    }

    // out[j] = sum_d P[j][d] * V2[j][d]
    #pragma unroll
    for (int mi = 0; mi < 4; ++mi)
        #pragma unroll
        for (int reg = 0; reg < 4; ++reg) {
            float s = 0.f;
            #pragma unroll
            for (int ni = 0; ni < 4; ++ni) s += accP[mi][ni][reg] * v2[mi][ni][reg];
            s += __shfl_xor(s, 1); s += __shfl_xor(s, 2);
            s += __shfl_xor(s, 4); s += __shfl_xor(s, 8);
            if ((lane & 15) == 0)
                part[(mi * 16 + (lane >> 4) * 4 + reg) * 4 + w] = s;
        }
    __syncthreads();
    if (t < 64)
        out[(size_t)rg * 256 + j0 + t] = part[t*4] + part[t*4+1] + part[t*4+2] + part[t*4+3];
}

extern "C" void kernel_launch(void* const* d_in, const int* in_sizes, int n_in,
                              void* d_out, int out_size, void* d_ws, size_t ws_size,
                              hipStream_t stream) {
    const float* layer1 = (const float*)d_in[0];
    const float* layer2 = (const float*)d_in[1];
    const float* h1     = (const float*)d_in[2];
    const float* h2     = (const float*)d_in[3];
    const float* W1     = (const float*)d_in[4];
    const float* W2     = (const float*)d_in[5];
    const float* W3     = (const float*)d_in[6];
    float* out = (float*)d_out;

    short* Wp1  = (short*)d_ws;                  // 33.55 MB
    short* Wp2  = Wp1 + 16777216;
    short* l1b  = Wp2 + 16777216;                // 2048x256
    short* l2b  = l1b + 524288;
    short* W3t  = l2b + 524288;                  // 256x256
    short* Wtp1 = W3t + 65536;                   // 256x256
    short* Wtp2 = Wtp1 + 65536;
    float* tail1 = (float*)(Wtp2 + 65536);       // 2048x256 fp32
    float* tail2 = tail1 + 524288;
    short* T1   = (short*)(tail2 + 524288);
    const size_t head = (size_t)(16777216*2 + 524288*2 + 65536*3) * 2 + (size_t)524288 * 2 * 4;
    int chunk = 2048;
    while (head + (size_t)chunk * 262144 > ws_size && chunk > 128) chunk >>= 1;
    short* T2 = T1 + (size_t)chunk * 65536;

    conv_bf16<<<1024, 256, 0, stream>>>(layer1, layer2, l1b, l2b);
    prep_w3t<<<64, 256, 0, stream>>>(W3, W3t);
    prep_wtail<<<dim3(64, 2), 256, 0, stream>>>(W1, W2, Wtp1, Wtp2);
    prep_wp<<<dim3(64, 256, 2), 256, 0, stream>>>(W1, W2, Wp1, Wp2);
    tail_mfma<<<dim3(16, 2, 2), 256, 0, stream>>>(l1b, Wtp1, Wtp2, W1, W2, tail1, tail2);

    for (int row0 = 0; row0 < 2048; row0 += chunk) {
        stage1<<<dim3(chunk / 128, 2, 512), 256, 0, stream>>>(
            l1b, Wp1, Wp2, W1, W2, T1, T2, row0);
        stage2<<<dim3(4, chunk), 256, 0, stream>>>(
            l2b, T1, T2, tail1, tail2, h1, h2, W3t, out, row0);
    }
}